// Round 7
// baseline (998.727 us; speedup 1.0000x reference)
//
#include <hip/hip_runtime.h>
#include <hip/hip_fp16.h>
#include <math.h>

#define NN 100000
#define EE 1600000
#define ET (EE + NN)   // 1,700,000 edges incl self-loops
#define FIN 128
#define D1 64          // H1*C1
#define H1 8
#define C1 8
#define C2 40
#define NEG 0.2f
#define EPSV 1e-16f
#define LOG2E 1.4426950408889634f

#define NBKT 391       // buckets of 256 dst: (99999>>8)+1
#define BCAPP 6784     // padded bucket capacity (cnt<=~4700 + 256*7 pad), %8==0
#define EBUF 5120      // LDS staging entries (unsorted cnt max ~4700)
#define CHUNK 2048     // edges per scatter block
#define NBB ((ET + CHUNK - 1) / CHUNK)   // 830
#define G1B ((NN + 63) / 64)             // 1563
#define PREPB 16
#define DB 32          // degree buckets (deg>>3, clamped)

typedef _Float16 f16x8 __attribute__((ext_vector_type(8)));
typedef float f32x4 __attribute__((ext_vector_type(4)));

__device__ __forceinline__ void edge_sd(int e, const int* __restrict__ ei, int& s, int& d) {
  if (e < EE) { s = ei[e]; d = ei[EE + e]; }
  else        { s = e - EE; d = s; }
}

// ---------- k1: scatter (blocks 0..NBB-1) || weight prep (blocks NBB..) ----------
__global__ __launch_bounds__(256) void k1_kernel(
    const int* __restrict__ ei, int* __restrict__ gcur, int* __restrict__ ecsr,
    const float* __restrict__ W1, const float* __restrict__ as1, const float* __restrict__ ad1,
    const float* __restrict__ W2, const float* __restrict__ as2, const float* __restrict__ ad2w,
    __half* __restrict__ Wf1, __half* __restrict__ Wf2) {
  __shared__ int lh[NBKT], lres[NBKT], lcur[NBKT];
  int t = threadIdx.x;
  if (blockIdx.x < NBB) {
    for (int i = t; i < NBKT; i += 256) { lh[i] = 0; lcur[i] = 0; }
    __syncthreads();
    int e0 = blockIdx.x * CHUNK;
    int e1 = min(e0 + CHUNK, ET);
    for (int e = e0 + t; e < e1; e += 256) {
      int d = (e < EE) ? ei[EE + e] : e - EE;
      atomicAdd(&lh[d >> 8], 1);
    }
    __syncthreads();
    for (int i = t; i < NBKT; i += 256)
      if (lh[i]) lres[i] = atomicAdd(&gcur[i], lh[i]);
    __syncthreads();
    for (int e = e0 + t; e < e1; e += 256) {
      int s, d; edge_sd(e, ei, s, d);
      int b = d >> 8;
      int lp = atomicAdd(&lcur[b], 1);
      ecsr[b * BCAPP + lres[b] + lp] = s | ((d & 255) << 17);
    }
  } else {
    int gid = (blockIdx.x - NBB) * 256 + t;
    int stride = PREPB * 256;
    for (int idx = gid; idx < 4 * 5 * 64 * 8; idx += stride) {
      int j = idx & 7, l = (idx >> 3) & 63;
      int g = idx >> 9;           // kk*5+ct
      int ct = g % 5, kk = g / 5;
      int kdim = kk * 32 + (l >> 4) * 8 + j;
      int c = l & 15;
      float v;
      if (ct < 4) v = W1[kdim * 64 + ct * 16 + c];
      else {
        const float* aw = (c < 8) ? as1 : ad1;
        int hh = c & 7;
        float acc = 0.f;
        for (int q = 0; q < 8; ++q) acc += W1[kdim * 64 + hh * 8 + q] * aw[hh * 8 + q];
        v = acc * LOG2E;
      }
      Wf1[idx] = __float2half(v);
    }
    for (int idx = gid; idx < 2 * 3 * 64 * 8; idx += stride) {
      int j = idx & 7, l = (idx >> 3) & 63;
      int g = idx >> 9;           // kk*3+ct
      int ct = g % 3, kk = g / 3;
      int kdim = kk * 32 + (l >> 4) * 8 + j;
      int c = ct * 16 + (l & 15);
      float v = 0.f;
      if (c < C2) v = W2[kdim * C2 + c];
      else if (c == 40 || c == 41) {
        const float* aw = (c == 40) ? as2 : ad2w;
        float acc = 0.f;
        for (int q = 0; q < C2; ++q) acc += W2[kdim * C2 + q] * aw[q];
        v = acc * LOG2E;
      }
      Wf2[idx] = __float2half(v);
    }
  }
}

// ---------- k2: bucket2csr w/ 8-aligned padded rows (blocks 0..NBKT-1) || gemm1 ----------
__global__ __launch_bounds__(256) void k2_kernel(
    const int* __restrict__ gcur, int2* __restrict__ rowrng, int* __restrict__ ecsr,
    int* __restrict__ dhist,
    const float* __restrict__ x, const __half* __restrict__ Wf1,
    __half* __restrict__ h, __half* __restrict__ as_h, float* __restrict__ ad) {
  __shared__ int ebuf[EBUF];     // 20 KB
  __shared__ int hist[256];
  __shared__ int sd[256];
  int t = threadIdx.x;
  if (blockIdx.x < NBKT) {
    int b = blockIdx.x;
    int base = b * BCAPP;
    int cnt = gcur[b];
    hist[t] = 0;
    __syncthreads();
    for (int i = t; i < cnt; i += 256) {
      int p = ecsr[base + i];
      ebuf[i] = p;
      atomicAdd(&hist[p >> 17], 1);
    }
    __syncthreads();
    int h0 = hist[t];              // degree of dst t
    int p8 = (h0 + 7) & ~7;        // padded length
    sd[t] = p8;
    __syncthreads();
    for (int off = 1; off < 256; off <<= 1) {
      int xv = sd[t];
      int yv = (t >= off) ? sd[t - off] : 0;
      __syncthreads();
      sd[t] = xv + yv;
      __syncthreads();
    }
    int runp = sd[t] - p8;         // padded exclusive base
    int g = b * 256 + t;
    if (g < NN) {
      rowrng[g] = make_int2(base + runp, base + runp + h0);
      atomicAdd(&dhist[min(h0 >> 3, DB - 1)], 1);
    }
    hist[t] = runp;
    __syncthreads();
    for (int i = t; i < cnt; i += 256) {
      int p = ebuf[i];
      int pos = atomicAdd(&hist[p >> 17], 1);
      ecsr[base + pos] = p & 0x1FFFF;
    }
    __syncthreads();
    if (g < NN && h0 < p8) {       // fill pads with first neighbor (deg>=1 always)
      int first = ecsr[base + runp];
      for (int q = runp + h0; q < runp + p8; ++q) ecsr[base + q] = first;
    }
  } else {
    // ---- gemm1: MFMA 64 nodes x 80 cols (64 ch + 16 att cols) ----
    int blk = blockIdx.x - NBKT;
    int w = t >> 6, lane = t & 63;
    int col = lane & 15, kg = lane >> 4;
    int node0 = blk * 64 + w * 16;
    int nodeA = min(node0 + col, NN - 1);
    const float* xr = x + (size_t)nodeA * FIN + kg * 8;
    const f16x8* Wq = (const f16x8*)Wf1;
    f32x4 acc0 = {0.f,0.f,0.f,0.f}, acc1 = acc0, acc2 = acc0, acc3 = acc0, acc4 = acc0;
#pragma unroll
    for (int kk = 0; kk < 4; ++kk) {
      float4 xa = *(const float4*)(xr + kk * 32);
      float4 xb = *(const float4*)(xr + kk * 32 + 4);
      f16x8 a;
      a[0] = (_Float16)xa.x; a[1] = (_Float16)xa.y; a[2] = (_Float16)xa.z; a[3] = (_Float16)xa.w;
      a[4] = (_Float16)xb.x; a[5] = (_Float16)xb.y; a[6] = (_Float16)xb.z; a[7] = (_Float16)xb.w;
      acc0 = __builtin_amdgcn_mfma_f32_16x16x32_f16(a, Wq[(kk * 5 + 0) * 64 + lane], acc0, 0, 0, 0);
      acc1 = __builtin_amdgcn_mfma_f32_16x16x32_f16(a, Wq[(kk * 5 + 1) * 64 + lane], acc1, 0, 0, 0);
      acc2 = __builtin_amdgcn_mfma_f32_16x16x32_f16(a, Wq[(kk * 5 + 2) * 64 + lane], acc2, 0, 0, 0);
      acc3 = __builtin_amdgcn_mfma_f32_16x16x32_f16(a, Wq[(kk * 5 + 3) * 64 + lane], acc3, 0, 0, 0);
      acc4 = __builtin_amdgcn_mfma_f32_16x16x32_f16(a, Wq[(kk * 5 + 4) * 64 + lane], acc4, 0, 0, 0);
    }
#pragma unroll
    for (int reg = 0; reg < 4; ++reg) {
      int nr = node0 + kg * 4 + reg;
      if (nr < NN) {
        h[(size_t)nr * 64 +  0 + col] = __float2half(acc0[reg]);
        h[(size_t)nr * 64 + 16 + col] = __float2half(acc1[reg]);
        h[(size_t)nr * 64 + 32 + col] = __float2half(acc2[reg]);
        h[(size_t)nr * 64 + 48 + col] = __float2half(acc3[reg]);
        float v = acc4[reg];
        if (col < 8) as_h[nr * 8 + col] = __float2half(v);
        else         ad[nr * 8 + col - 8] = v;
      }
    }
  }
}

// ---------- k3: degree-balanced permutation (counting sort by deg>>3) ----------
__global__ __launch_bounds__(256) void k3_kernel(
    const int2* __restrict__ rowrng, const int* __restrict__ dhist,
    int* __restrict__ dcur, int* __restrict__ perm) {
  __shared__ int lh[DB], lres[DB], lcur[DB];
  int t = threadIdx.x;
  if (t < DB) { lh[t] = 0; lcur[t] = 0; }
  __syncthreads();
  int n = blockIdx.x * 256 + t;
  int bkt = 0;
  if (n < NN) {
    int2 rr = rowrng[n];
    bkt = min((rr.y - rr.x) >> 3, DB - 1);
    atomicAdd(&lh[bkt], 1);
  }
  __syncthreads();
  if (t < DB && lh[t]) lres[t] = atomicAdd(&dcur[t], lh[t]);
  __syncthreads();
  if (n < NN) {
    int lp = atomicAdd(&lcur[bkt], 1);
    int base = 0;
    for (int q = 0; q < bkt; ++q) base += dhist[q];
    perm[base + lres[bkt] + lp] = n;
  }
}

// consume one edge's message
#define CONS(u, avh, valid) do { \
    float xx = __half2float(avh) + adv; xx = fmaxf(xx, NEG * xx); \
    float e = (valid) ? exp2f(xx) : 0.f; den += e; \
    float2 f; \
    f = __half22float2(*(const __half2*)&(u).x); a0 = fmaf(f.x, e, a0); a1 = fmaf(f.y, e, a1); \
    f = __half22float2(*(const __half2*)&(u).y); a2 = fmaf(f.x, e, a2); a3 = fmaf(f.y, e, a3); \
    f = __half22float2(*(const __half2*)&(u).z); a4 = fmaf(f.x, e, a4); a5 = fmaf(f.y, e, a5); \
    f = __half22float2(*(const __half2*)&(u).w); a6 = fmaf(f.x, e, a6); a7 = fmaf(f.y, e, a7); \
  } while (0)

// issue 8 gathers from csr[beg+OFF..+7] (8-aligned, pad-filled) -- no shfl
#define ISSUE1(OFF, U, V) do { \
    int4 c0_ = *(const int4*)&csr[beg + (OFF)]; \
    int4 c1_ = *(const int4*)&csr[beg + (OFF) + 4]; \
    int sj_[8] = {c0_.x, c0_.y, c0_.z, c0_.w, c1_.x, c1_.y, c1_.z, c1_.w}; \
    _Pragma("unroll") \
    for (int r_ = 0; r_ < 8; ++r_) { \
      U[r_] = *(const uint4*)(h + ((size_t)(uint)sj_[r_] << 6) + (k << 3)); \
      V[r_] = as_h[(uint)sj_[r_] * 8u + k]; \
    } \
  } while (0)

// ---------- fused aggregation, layer 1: octet-per-node, degree-balanced ----------
__global__ __launch_bounds__(256) void agg1_kernel(
    const int* __restrict__ perm,
    const int2* __restrict__ rowrng, const int* __restrict__ csr,
    const __half* __restrict__ as_h, const float* __restrict__ ad,
    const __half* __restrict__ h, const float* __restrict__ b1,
    float* __restrict__ emb) {
  int t = threadIdx.x;
  int lane = t & 63;
  int o = lane >> 3, k = lane & 7;
  int node = perm[blockIdx.x * 32 + (t >> 6) * 8 + o];   // NN%32==0
  int2 rr = rowrng[node];
  int beg = rr.x, deg = rr.y - rr.x;
  float adv = ad[node * 8 + k];
  float den = 0.f;
  float a0=0.f,a1=0.f,a2=0.f,a3=0.f,a4=0.f,a5=0.f,a6=0.f,a7=0.f;
  uint4 uA[8]; __half vA[8];
  ISSUE1(0, uA, vA);
  for (int i = 0; i < deg; i += 16) {
    uint4 uB[8]; __half vB[8];
    bool haveB = (i + 8 < deg);
    if (haveB) ISSUE1(i + 8, uB, vB);
#pragma unroll
    for (int r = 0; r < 8; ++r) CONS(uA[r], vA[r], i + r < deg);
    if (i + 16 < deg) ISSUE1(i + 16, uA, vA);
    if (haveB) {
#pragma unroll
      for (int r = 0; r < 8; ++r) CONS(uB[r], vB[r], i + 8 + r < deg);
    }
  }
  float4 bv0 = ((const float4*)b1)[2 * k];
  float4 bv1 = ((const float4*)b1)[2 * k + 1];
  float inv = 1.0f / (den + EPSV);
  float v0 = fmaf(a0, inv, bv0.x), v1 = fmaf(a1, inv, bv0.y);
  float v2 = fmaf(a2, inv, bv0.z), v3 = fmaf(a3, inv, bv0.w);
  float v4 = fmaf(a4, inv, bv1.x), v5 = fmaf(a5, inv, bv1.y);
  float v6 = fmaf(a6, inv, bv1.z), v7 = fmaf(a7, inv, bv1.w);
  v0 = v0 > 0.f ? v0 : expm1f(v0); v1 = v1 > 0.f ? v1 : expm1f(v1);
  v2 = v2 > 0.f ? v2 : expm1f(v2); v3 = v3 > 0.f ? v3 : expm1f(v3);
  v4 = v4 > 0.f ? v4 : expm1f(v4); v5 = v5 > 0.f ? v5 : expm1f(v5);
  v6 = v6 > 0.f ? v6 : expm1f(v6); v7 = v7 > 0.f ? v7 : expm1f(v7);
  float4 s0; s0.x = v0; s0.y = v1; s0.z = v2; s0.w = v3;
  float4 s1; s1.x = v4; s1.y = v5; s1.z = v6; s1.w = v7;
  float* ep = emb + (size_t)node * D1 + (k << 3);
  ((float4*)ep)[0] = s0; ((float4*)ep)[1] = s1;
}

// ---------- layer 2: MFMA GEMM (64 nodes x 48 cols incl att cols) ----------
__global__ __launch_bounds__(256) void gemm2_kernel(
    const float* __restrict__ emb, const __half* __restrict__ Wf2,
    __half* __restrict__ h2, float* __restrict__ ad2) {
  int t = threadIdx.x;
  int w = t >> 6, lane = t & 63;
  int col = lane & 15, kg = lane >> 4;
  int node0 = blockIdx.x * 64 + w * 16;
  int nodeA = min(node0 + col, NN - 1);
  const float* er = emb + (size_t)nodeA * D1 + kg * 8;
  const f16x8* Wq = (const f16x8*)Wf2;
  f32x4 acc0 = {0.f,0.f,0.f,0.f}, acc1 = acc0, acc2 = acc0;
#pragma unroll
  for (int kk = 0; kk < 2; ++kk) {
    float4 xa = *(const float4*)(er + kk * 32);
    float4 xb = *(const float4*)(er + kk * 32 + 4);
    f16x8 a;
    a[0] = (_Float16)xa.x; a[1] = (_Float16)xa.y; a[2] = (_Float16)xa.z; a[3] = (_Float16)xa.w;
    a[4] = (_Float16)xb.x; a[5] = (_Float16)xb.y; a[6] = (_Float16)xb.z; a[7] = (_Float16)xb.w;
    acc0 = __builtin_amdgcn_mfma_f32_16x16x32_f16(a, Wq[(kk * 3 + 0) * 64 + lane], acc0, 0, 0, 0);
    acc1 = __builtin_amdgcn_mfma_f32_16x16x32_f16(a, Wq[(kk * 3 + 1) * 64 + lane], acc1, 0, 0, 0);
    acc2 = __builtin_amdgcn_mfma_f32_16x16x32_f16(a, Wq[(kk * 3 + 2) * 64 + lane], acc2, 0, 0, 0);
  }
#pragma unroll
  for (int reg = 0; reg < 4; ++reg) {
    int nr = node0 + kg * 4 + reg;
    if (nr < NN) {
      h2[(size_t)nr * 64 +  0 + col] = __float2half(acc0[reg]);
      h2[(size_t)nr * 64 + 16 + col] = __float2half(acc1[reg]);
      float v = acc2[reg];
      if (col < 8)       h2[(size_t)nr * 64 + 32 + col] = __float2half(v);
      else if (col == 8) h2[(size_t)nr * 64 + 40] = __float2half(v);
      else if (col == 9) ad2[nr] = v;
    }
  }
}

#define ISSUE2(OFF, U, V) do { \
    int4 c0_ = *(const int4*)&csr[beg + (OFF)]; \
    int4 c1_ = *(const int4*)&csr[beg + (OFF) + 4]; \
    int sj_[8] = {c0_.x, c0_.y, c0_.z, c0_.w, c1_.x, c1_.y, c1_.z, c1_.w}; \
    _Pragma("unroll") \
    for (int r_ = 0; r_ < 8; ++r_) { \
      const __half* rp_ = h2 + ((size_t)(uint)sj_[r_] << 6); \
      U[r_] = *(const uint4*)(rp_ + (kc << 3)); \
      V[r_] = rp_[40]; \
    } \
  } while (0)

// ---------- fused aggregation, layer 2 + log_softmax: octet-per-node, balanced ----------
__global__ __launch_bounds__(256) void agg2_kernel(
    const int* __restrict__ perm,
    const int2* __restrict__ rowrng, const int* __restrict__ csr,
    const float* __restrict__ ad, const __half* __restrict__ h2,
    const float* __restrict__ b2, float* __restrict__ out) {
  int t = threadIdx.x;
  int lane = t & 63;
  int o = lane >> 3, k = lane & 7;
  int kc = min(k, 4);
  int node = perm[blockIdx.x * 32 + (t >> 6) * 8 + o];
  int2 rr = rowrng[node];
  int beg = rr.x, deg = rr.y - rr.x;
  float adv = ad[node];
  float den = 0.f;
  float a0=0.f,a1=0.f,a2=0.f,a3=0.f,a4=0.f,a5=0.f,a6=0.f,a7=0.f;
  uint4 uA[8]; __half vA[8];
  ISSUE2(0, uA, vA);
  for (int i = 0; i < deg; i += 16) {
    uint4 uB[8]; __half vB[8];
    bool haveB = (i + 8 < deg);
    if (haveB) ISSUE2(i + 8, uB, vB);
#pragma unroll
    for (int r = 0; r < 8; ++r) CONS(uA[r], vA[r], i + r < deg);
    if (i + 16 < deg) ISSUE2(i + 16, uA, vA);
    if (haveB) {
#pragma unroll
      for (int r = 0; r < 8; ++r) CONS(uB[r], vB[r], i + 8 + r < deg);
    }
  }
  float4 bv0 = ((const float4*)b2)[2 * kc];
  float4 bv1 = ((const float4*)b2)[2 * kc + 1];
  float inv = 1.0f / (den + EPSV);
  float v0 = fmaf(a0, inv, bv0.x), v1 = fmaf(a1, inv, bv0.y);
  float v2 = fmaf(a2, inv, bv0.z), v3 = fmaf(a3, inv, bv0.w);
  float v4 = fmaf(a4, inv, bv1.x), v5 = fmaf(a5, inv, bv1.y);
  float v6 = fmaf(a6, inv, bv1.z), v7 = fmaf(a7, inv, bv1.w);
  bool act = (k < 5);
  float m = act ? fmaxf(fmaxf(fmaxf(v0, v1), fmaxf(v2, v3)),
                        fmaxf(fmaxf(v4, v5), fmaxf(v6, v7))) : -INFINITY;
#pragma unroll
  for (int off = 1; off < 8; off <<= 1) m = fmaxf(m, __shfl_xor(m, off, 64));
  float ex = act ? (__expf(v0 - m) + __expf(v1 - m) + __expf(v2 - m) + __expf(v3 - m) +
                    __expf(v4 - m) + __expf(v5 - m) + __expf(v6 - m) + __expf(v7 - m)) : 0.f;
#pragma unroll
  for (int off = 1; off < 8; off <<= 1) ex += __shfl_xor(ex, off, 64);
  if (act) {
    float lls = m + logf(ex);
    float4 s0; s0.x = v0 - lls; s0.y = v1 - lls; s0.z = v2 - lls; s0.w = v3 - lls;
    float4 s1; s1.x = v4 - lls; s1.y = v5 - lls; s1.z = v6 - lls; s1.w = v7 - lls;
    float* op = out + (size_t)node * C2 + (k << 3);
    ((float4*)op)[0] = s0; ((float4*)op)[1] = s1;
  }
}

// ---------- launch ----------
extern "C" void kernel_launch(void* const* d_in, const int* in_sizes, int n_in,
                              void* d_out, int out_size, void* d_ws, size_t ws_size,
                              hipStream_t stream) {
  const float* x    = (const float*)d_in[0];
  const float* W1   = (const float*)d_in[1];
  const float* as1w = (const float*)d_in[2];
  const float* ad1w = (const float*)d_in[3];
  const float* b1   = (const float*)d_in[4];
  const float* W2   = (const float*)d_in[5];
  const float* as2w = (const float*)d_in[6];
  const float* ad2w = (const float*)d_in[7];
  const float* b2   = (const float*)d_in[8];
  const int*   ei   = (const int*)d_in[9];

  float* out   = (float*)d_out;
  float* outls = out;                    // [N,40] log_softmax
  float* emb   = out + (long)NN * C2;    // [N,64] emb

  char* wsb = (char*)d_ws;
  __half* h1   = (__half*)wsb; wsb += sizeof(__half) * (size_t)NN * D1;
  __half* h2   = (__half*)wsb; wsb += sizeof(__half) * ((size_t)NN * 64 + 64);
  __half* ash1 = (__half*)wsb; wsb += sizeof(__half) * (size_t)NN * H1;
  float* adst1 = (float*)wsb; wsb += sizeof(float) * (size_t)NN * H1;
  float* adst2 = (float*)wsb; wsb += sizeof(float) * (size_t)NN;
  int2* rowrng = (int2*)wsb;  wsb += sizeof(int2) * (size_t)NN;
  int* perm    = (int*)wsb;   wsb += sizeof(int) * (size_t)NN;
  int* gcur    = (int*)wsb;   wsb += sizeof(int) * (NBKT + 4);
  int* dhist   = (int*)wsb;   wsb += sizeof(int) * DB;
  int* dcur    = (int*)wsb;   wsb += sizeof(int) * DB;
  __half* Wf1  = (__half*)wsb; wsb += sizeof(__half) * 4 * 5 * 64 * 8;
  __half* Wf2  = (__half*)wsb; wsb += sizeof(__half) * 2 * 3 * 64 * 8;
  int* ecsr    = (int*)wsb;   wsb += sizeof(int) * (size_t)NBKT * BCAPP;

  hipMemsetAsync(gcur, 0, sizeof(int) * (NBKT + 4 + 2 * DB), stream);
  // k1: scatter || prep
  k1_kernel<<<NBB + PREPB, 256, 0, stream>>>(ei, gcur, ecsr,
                                             W1, as1w, ad1w, W2, as2w, ad2w, Wf1, Wf2);
  // k2: bucket2csr (padded) || gemm1
  k2_kernel<<<NBKT + G1B, 256, 0, stream>>>(gcur, rowrng, ecsr, dhist,
                                            x, Wf1, h1, ash1, adst1);
  // k3: degree-balanced perm
  k3_kernel<<<(NN + 255) / 256, 256, 0, stream>>>(rowrng, dhist, dcur, perm);
  // layer-1 aggregation
  agg1_kernel<<<NN / 32, 256, 0, stream>>>(perm, rowrng, ecsr, ash1, adst1, h1, b1, emb);
  // layer 2
  gemm2_kernel<<<(NN + 63) / 64, 256, 0, stream>>>(emb, Wf2, h2, adst2);
  agg2_kernel<<<NN / 32, 256, 0, stream>>>(perm, rowrng, ecsr, adst2, h2, b2, outls);
}

// Round 8
// 261.945 us; speedup vs baseline: 3.8127x; 3.8127x over previous
//
#include <hip/hip_runtime.h>
#include <hip/hip_fp16.h>
#include <math.h>

#define NN 100000
#define EE 1600000
#define ET (EE + NN)   // 1,700,000 edges incl self-loops
#define FIN 128
#define D1 64          // H1*C1
#define H1 8
#define C1 8
#define C2 40
#define NEG 0.2f
#define EPSV 1e-16f
#define LOG2E 1.4426950408889634f

#define NBKT 391       // buckets of 256 dst: (99999>>8)+1
#define BCAPP 6784     // padded bucket capacity (cnt<=~4700 + 256*7 pad), %8==0
#define EBUF 5120      // LDS staging entries (unsorted cnt max ~4700)
#define CHUNK 2048     // edges per scatter block
#define NBB ((ET + CHUNK - 1) / CHUNK)
#define G1B ((NN + 63) / 64)             // 1563
#define PREPB 16
#define DB 32          // degree buckets (deg>>3, clamped)
#define DSTR 32        // dhist/dcur stride in ints (128B: one line per bin)

typedef _Float16 f16x8 __attribute__((ext_vector_type(8)));
typedef float f32x4 __attribute__((ext_vector_type(4)));

__device__ __forceinline__ void edge_sd(int e, const int* __restrict__ ei, int& s, int& d) {
  if (e < EE) { s = ei[e]; d = ei[EE + e]; }
  else        { s = e - EE; d = s; }
}

// ---------- k1: scatter (blocks 0..NBB-1) || weight prep (blocks NBB..) ----------
__global__ __launch_bounds__(256) void k1_kernel(
    const int* __restrict__ ei, int* __restrict__ gcur, int* __restrict__ ecsr,
    const float* __restrict__ W1, const float* __restrict__ as1, const float* __restrict__ ad1,
    const float* __restrict__ W2, const float* __restrict__ as2, const float* __restrict__ ad2w,
    __half* __restrict__ Wf1, __half* __restrict__ Wf2) {
  __shared__ int lh[NBKT], lres[NBKT], lcur[NBKT];
  int t = threadIdx.x;
  if (blockIdx.x < NBB) {
    for (int i = t; i < NBKT; i += 256) { lh[i] = 0; lcur[i] = 0; }
    __syncthreads();
    int e0 = blockIdx.x * CHUNK;
    int e1 = min(e0 + CHUNK, ET);
    for (int e = e0 + t; e < e1; e += 256) {
      int d = (e < EE) ? ei[EE + e] : e - EE;
      atomicAdd(&lh[d >> 8], 1);
    }
    __syncthreads();
    for (int i = t; i < NBKT; i += 256)
      if (lh[i]) lres[i] = atomicAdd(&gcur[i], lh[i]);
    __syncthreads();
    for (int e = e0 + t; e < e1; e += 256) {
      int s, d; edge_sd(e, ei, s, d);
      int b = d >> 8;
      int lp = atomicAdd(&lcur[b], 1);
      ecsr[b * BCAPP + lres[b] + lp] = s | ((d & 255) << 17);
    }
  } else {
    int gid = (blockIdx.x - NBB) * 256 + t;
    int stride = PREPB * 256;
    for (int idx = gid; idx < 4 * 5 * 64 * 8; idx += stride) {
      int j = idx & 7, l = (idx >> 3) & 63;
      int g = idx >> 9;           // kk*5+ct
      int ct = g % 5, kk = g / 5;
      int kdim = kk * 32 + (l >> 4) * 8 + j;
      int c = l & 15;
      float v;
      if (ct < 4) v = W1[kdim * 64 + ct * 16 + c];
      else {
        const float* aw = (c < 8) ? as1 : ad1;
        int hh = c & 7;
        float acc = 0.f;
        for (int q = 0; q < 8; ++q) acc += W1[kdim * 64 + hh * 8 + q] * aw[hh * 8 + q];
        v = acc * LOG2E;
      }
      Wf1[idx] = __float2half(v);
    }
    for (int idx = gid; idx < 2 * 3 * 64 * 8; idx += stride) {
      int j = idx & 7, l = (idx >> 3) & 63;
      int g = idx >> 9;           // kk*3+ct
      int ct = g % 3, kk = g / 3;
      int kdim = kk * 32 + (l >> 4) * 8 + j;
      int c = ct * 16 + (l & 15);
      float v = 0.f;
      if (c < C2) v = W2[kdim * C2 + c];
      else if (c == 40 || c == 41) {
        const float* aw = (c == 40) ? as2 : ad2w;
        float acc = 0.f;
        for (int q = 0; q < C2; ++q) acc += W2[kdim * C2 + q] * aw[q];
        v = acc * LOG2E;
      }
      Wf2[idx] = __float2half(v);
    }
  }
}

// ---------- k2: bucket2csr w/ 8-aligned padded rows || gemm1 ----------
// degree histogram: LDS-aggregated, <=DB global atomics/block onto padded bins
__global__ __launch_bounds__(256) void k2_kernel(
    const int* __restrict__ gcur, int2* __restrict__ rowrng, int* __restrict__ ecsr,
    int* __restrict__ dhist,
    const float* __restrict__ x, const __half* __restrict__ Wf1,
    __half* __restrict__ h, __half* __restrict__ as_h, float* __restrict__ ad) {
  __shared__ int ebuf[EBUF];     // 20 KB
  __shared__ int hist[256];
  __shared__ int sd[256];
  __shared__ int ldh[DB];
  int t = threadIdx.x;
  if (blockIdx.x < NBKT) {
    int b = blockIdx.x;
    int base = b * BCAPP;
    int cnt = gcur[b];
    hist[t] = 0;
    if (t < DB) ldh[t] = 0;
    __syncthreads();
    for (int i = t; i < cnt; i += 256) {
      int p = ecsr[base + i];
      ebuf[i] = p;
      atomicAdd(&hist[p >> 17], 1);
    }
    __syncthreads();
    int h0 = hist[t];              // degree of dst t
    int p8 = (h0 + 7) & ~7;        // padded length
    sd[t] = p8;
    __syncthreads();
    for (int off = 1; off < 256; off <<= 1) {
      int xv = sd[t];
      int yv = (t >= off) ? sd[t - off] : 0;
      __syncthreads();
      sd[t] = xv + yv;
      __syncthreads();
    }
    int runp = sd[t] - p8;         // padded exclusive base
    int g = b * 256 + t;
    if (g < NN) {
      rowrng[g] = make_int2(base + runp, base + runp + h0);
      atomicAdd(&ldh[min(h0 >> 3, DB - 1)], 1);   // LDS, cheap
    }
    hist[t] = runp;
    __syncthreads();
    if (t < DB && ldh[t]) atomicAdd(&dhist[t * DSTR], ldh[t]);  // <=DB global/block
    for (int i = t; i < cnt; i += 256) {
      int p = ebuf[i];
      int pos = atomicAdd(&hist[p >> 17], 1);
      ecsr[base + pos] = p & 0x1FFFF;
    }
    __syncthreads();
    if (g < NN && h0 < p8) {       // fill pads with first neighbor (deg>=1 always)
      int first = ecsr[base + runp];
      for (int q = runp + h0; q < runp + p8; ++q) ecsr[base + q] = first;
    }
  } else {
    // ---- gemm1: MFMA 64 nodes x 80 cols (64 ch + 16 att cols) ----
    int blk = blockIdx.x - NBKT;
    int w = t >> 6, lane = t & 63;
    int col = lane & 15, kg = lane >> 4;
    int node0 = blk * 64 + w * 16;
    int nodeA = min(node0 + col, NN - 1);
    const float* xr = x + (size_t)nodeA * FIN + kg * 8;
    const f16x8* Wq = (const f16x8*)Wf1;
    f32x4 acc0 = {0.f,0.f,0.f,0.f}, acc1 = acc0, acc2 = acc0, acc3 = acc0, acc4 = acc0;
#pragma unroll
    for (int kk = 0; kk < 4; ++kk) {
      float4 xa = *(const float4*)(xr + kk * 32);
      float4 xb = *(const float4*)(xr + kk * 32 + 4);
      f16x8 a;
      a[0] = (_Float16)xa.x; a[1] = (_Float16)xa.y; a[2] = (_Float16)xa.z; a[3] = (_Float16)xa.w;
      a[4] = (_Float16)xb.x; a[5] = (_Float16)xb.y; a[6] = (_Float16)xb.z; a[7] = (_Float16)xb.w;
      acc0 = __builtin_amdgcn_mfma_f32_16x16x32_f16(a, Wq[(kk * 5 + 0) * 64 + lane], acc0, 0, 0, 0);
      acc1 = __builtin_amdgcn_mfma_f32_16x16x32_f16(a, Wq[(kk * 5 + 1) * 64 + lane], acc1, 0, 0, 0);
      acc2 = __builtin_amdgcn_mfma_f32_16x16x32_f16(a, Wq[(kk * 5 + 2) * 64 + lane], acc2, 0, 0, 0);
      acc3 = __builtin_amdgcn_mfma_f32_16x16x32_f16(a, Wq[(kk * 5 + 3) * 64 + lane], acc3, 0, 0, 0);
      acc4 = __builtin_amdgcn_mfma_f32_16x16x32_f16(a, Wq[(kk * 5 + 4) * 64 + lane], acc4, 0, 0, 0);
    }
#pragma unroll
    for (int reg = 0; reg < 4; ++reg) {
      int nr = node0 + kg * 4 + reg;
      if (nr < NN) {
        h[(size_t)nr * 64 +  0 + col] = __float2half(acc0[reg]);
        h[(size_t)nr * 64 + 16 + col] = __float2half(acc1[reg]);
        h[(size_t)nr * 64 + 32 + col] = __float2half(acc2[reg]);
        h[(size_t)nr * 64 + 48 + col] = __float2half(acc3[reg]);
        float v = acc4[reg];
        if (col < 8) as_h[nr * 8 + col] = __float2half(v);
        else         ad[nr * 8 + col - 8] = v;
      }
    }
  }
}

// ---------- k3: degree-balanced permutation (counting sort by deg>>3) ----------
__global__ __launch_bounds__(256) void k3_kernel(
    const int2* __restrict__ rowrng, const int* __restrict__ dhist,
    int* __restrict__ dcur, int* __restrict__ perm) {
  __shared__ int lh[DB], lres[DB], lcur[DB], pbase[DB];
  int t = threadIdx.x;
  if (t < DB) { lh[t] = 0; lcur[t] = 0; }
  __syncthreads();
  int n = blockIdx.x * 256 + t;
  int bkt = 0;
  if (n < NN) {
    int2 rr = rowrng[n];
    bkt = min((rr.y - rr.x) >> 3, DB - 1);
    atomicAdd(&lh[bkt], 1);
  }
  __syncthreads();
  if (t == 0) {
    int acc = 0;
    for (int q = 0; q < DB; ++q) { pbase[q] = acc; acc += dhist[q * DSTR]; }
  }
  if (t < DB && lh[t]) lres[t] = atomicAdd(&dcur[t * DSTR], lh[t]);
  __syncthreads();
  if (n < NN) {
    int lp = atomicAdd(&lcur[bkt], 1);
    perm[pbase[bkt] + lres[bkt] + lp] = n;
  }
}

// consume one edge's message
#define CONS(u, avh, valid) do { \
    float xx = __half2float(avh) + adv; xx = fmaxf(xx, NEG * xx); \
    float e = (valid) ? exp2f(xx) : 0.f; den += e; \
    float2 f; \
    f = __half22float2(*(const __half2*)&(u).x); a0 = fmaf(f.x, e, a0); a1 = fmaf(f.y, e, a1); \
    f = __half22float2(*(const __half2*)&(u).y); a2 = fmaf(f.x, e, a2); a3 = fmaf(f.y, e, a3); \
    f = __half22float2(*(const __half2*)&(u).z); a4 = fmaf(f.x, e, a4); a5 = fmaf(f.y, e, a5); \
    f = __half22float2(*(const __half2*)&(u).w); a6 = fmaf(f.x, e, a6); a7 = fmaf(f.y, e, a7); \
  } while (0)

// issue 8 gathers from csr[beg+OFF..+7] (8-aligned, pad-filled) -- no shfl
#define ISSUE1(OFF, U, V) do { \
    int4 c0_ = *(const int4*)&csr[beg + (OFF)]; \
    int4 c1_ = *(const int4*)&csr[beg + (OFF) + 4]; \
    int sj_[8] = {c0_.x, c0_.y, c0_.z, c0_.w, c1_.x, c1_.y, c1_.z, c1_.w}; \
    _Pragma("unroll") \
    for (int r_ = 0; r_ < 8; ++r_) { \
      U[r_] = *(const uint4*)(h + ((size_t)(uint)sj_[r_] << 6) + (k << 3)); \
      V[r_] = as_h[(uint)sj_[r_] * 8u + k]; \
    } \
  } while (0)

// ---------- fused aggregation, layer 1: octet-per-node, degree-balanced ----------
__global__ __launch_bounds__(256) void agg1_kernel(
    const int* __restrict__ perm,
    const int2* __restrict__ rowrng, const int* __restrict__ csr,
    const __half* __restrict__ as_h, const float* __restrict__ ad,
    const __half* __restrict__ h, const float* __restrict__ b1,
    float* __restrict__ emb) {
  int t = threadIdx.x;
  int lane = t & 63;
  int o = lane >> 3, k = lane & 7;
  int node = perm[blockIdx.x * 32 + (t >> 6) * 8 + o];   // NN%32==0
  int2 rr = rowrng[node];
  int beg = rr.x, deg = rr.y - rr.x;
  float adv = ad[node * 8 + k];
  float den = 0.f;
  float a0=0.f,a1=0.f,a2=0.f,a3=0.f,a4=0.f,a5=0.f,a6=0.f,a7=0.f;
  uint4 uA[8]; __half vA[8];
  ISSUE1(0, uA, vA);
  for (int i = 0; i < deg; i += 16) {
    uint4 uB[8]; __half vB[8];
    bool haveB = (i + 8 < deg);
    if (haveB) ISSUE1(i + 8, uB, vB);
#pragma unroll
    for (int r = 0; r < 8; ++r) CONS(uA[r], vA[r], i + r < deg);
    if (i + 16 < deg) ISSUE1(i + 16, uA, vA);
    if (haveB) {
#pragma unroll
      for (int r = 0; r < 8; ++r) CONS(uB[r], vB[r], i + 8 + r < deg);
    }
  }
  float4 bv0 = ((const float4*)b1)[2 * k];
  float4 bv1 = ((const float4*)b1)[2 * k + 1];
  float inv = 1.0f / (den + EPSV);
  float v0 = fmaf(a0, inv, bv0.x), v1 = fmaf(a1, inv, bv0.y);
  float v2 = fmaf(a2, inv, bv0.z), v3 = fmaf(a3, inv, bv0.w);
  float v4 = fmaf(a4, inv, bv1.x), v5 = fmaf(a5, inv, bv1.y);
  float v6 = fmaf(a6, inv, bv1.z), v7 = fmaf(a7, inv, bv1.w);
  v0 = v0 > 0.f ? v0 : expm1f(v0); v1 = v1 > 0.f ? v1 : expm1f(v1);
  v2 = v2 > 0.f ? v2 : expm1f(v2); v3 = v3 > 0.f ? v3 : expm1f(v3);
  v4 = v4 > 0.f ? v4 : expm1f(v4); v5 = v5 > 0.f ? v5 : expm1f(v5);
  v6 = v6 > 0.f ? v6 : expm1f(v6); v7 = v7 > 0.f ? v7 : expm1f(v7);
  float4 s0; s0.x = v0; s0.y = v1; s0.z = v2; s0.w = v3;
  float4 s1; s1.x = v4; s1.y = v5; s1.z = v6; s1.w = v7;
  float* ep = emb + (size_t)node * D1 + (k << 3);
  ((float4*)ep)[0] = s0; ((float4*)ep)[1] = s1;
}

// ---------- layer 2: MFMA GEMM (64 nodes x 48 cols incl att cols) ----------
__global__ __launch_bounds__(256) void gemm2_kernel(
    const float* __restrict__ emb, const __half* __restrict__ Wf2,
    __half* __restrict__ h2, float* __restrict__ ad2) {
  int t = threadIdx.x;
  int w = t >> 6, lane = t & 63;
  int col = lane & 15, kg = lane >> 4;
  int node0 = blockIdx.x * 64 + w * 16;
  int nodeA = min(node0 + col, NN - 1);
  const float* er = emb + (size_t)nodeA * D1 + kg * 8;
  const f16x8* Wq = (const f16x8*)Wf2;
  f32x4 acc0 = {0.f,0.f,0.f,0.f}, acc1 = acc0, acc2 = acc0;
#pragma unroll
  for (int kk = 0; kk < 2; ++kk) {
    float4 xa = *(const float4*)(er + kk * 32);
    float4 xb = *(const float4*)(er + kk * 32 + 4);
    f16x8 a;
    a[0] = (_Float16)xa.x; a[1] = (_Float16)xa.y; a[2] = (_Float16)xa.z; a[3] = (_Float16)xa.w;
    a[4] = (_Float16)xb.x; a[5] = (_Float16)xb.y; a[6] = (_Float16)xb.z; a[7] = (_Float16)xb.w;
    acc0 = __builtin_amdgcn_mfma_f32_16x16x32_f16(a, Wq[(kk * 3 + 0) * 64 + lane], acc0, 0, 0, 0);
    acc1 = __builtin_amdgcn_mfma_f32_16x16x32_f16(a, Wq[(kk * 3 + 1) * 64 + lane], acc1, 0, 0, 0);
    acc2 = __builtin_amdgcn_mfma_f32_16x16x32_f16(a, Wq[(kk * 3 + 2) * 64 + lane], acc2, 0, 0, 0);
  }
#pragma unroll
  for (int reg = 0; reg < 4; ++reg) {
    int nr = node0 + kg * 4 + reg;
    if (nr < NN) {
      h2[(size_t)nr * 64 +  0 + col] = __float2half(acc0[reg]);
      h2[(size_t)nr * 64 + 16 + col] = __float2half(acc1[reg]);
      float v = acc2[reg];
      if (col < 8)       h2[(size_t)nr * 64 + 32 + col] = __float2half(v);
      else if (col == 8) h2[(size_t)nr * 64 + 40] = __float2half(v);
      else if (col == 9) ad2[nr] = v;
    }
  }
}

#define ISSUE2(OFF, U, V) do { \
    int4 c0_ = *(const int4*)&csr[beg + (OFF)]; \
    int4 c1_ = *(const int4*)&csr[beg + (OFF) + 4]; \
    int sj_[8] = {c0_.x, c0_.y, c0_.z, c0_.w, c1_.x, c1_.y, c1_.z, c1_.w}; \
    _Pragma("unroll") \
    for (int r_ = 0; r_ < 8; ++r_) { \
      const __half* rp_ = h2 + ((size_t)(uint)sj_[r_] << 6); \
      U[r_] = *(const uint4*)(rp_ + (kc << 3)); \
      V[r_] = rp_[40]; \
    } \
  } while (0)

// ---------- fused aggregation, layer 2 + log_softmax: octet-per-node, balanced ----------
__global__ __launch_bounds__(256) void agg2_kernel(
    const int* __restrict__ perm,
    const int2* __restrict__ rowrng, const int* __restrict__ csr,
    const float* __restrict__ ad, const __half* __restrict__ h2,
    const float* __restrict__ b2, float* __restrict__ out) {
  int t = threadIdx.x;
  int lane = t & 63;
  int o = lane >> 3, k = lane & 7;
  int kc = min(k, 4);
  int node = perm[blockIdx.x * 32 + (t >> 6) * 8 + o];
  int2 rr = rowrng[node];
  int beg = rr.x, deg = rr.y - rr.x;
  float adv = ad[node];
  float den = 0.f;
  float a0=0.f,a1=0.f,a2=0.f,a3=0.f,a4=0.f,a5=0.f,a6=0.f,a7=0.f;
  uint4 uA[8]; __half vA[8];
  ISSUE2(0, uA, vA);
  for (int i = 0; i < deg; i += 16) {
    uint4 uB[8]; __half vB[8];
    bool haveB = (i + 8 < deg);
    if (haveB) ISSUE2(i + 8, uB, vB);
#pragma unroll
    for (int r = 0; r < 8; ++r) CONS(uA[r], vA[r], i + r < deg);
    if (i + 16 < deg) ISSUE2(i + 16, uA, vA);
    if (haveB) {
#pragma unroll
      for (int r = 0; r < 8; ++r) CONS(uB[r], vB[r], i + 8 + r < deg);
    }
  }
  float4 bv0 = ((const float4*)b2)[2 * kc];
  float4 bv1 = ((const float4*)b2)[2 * kc + 1];
  float inv = 1.0f / (den + EPSV);
  float v0 = fmaf(a0, inv, bv0.x), v1 = fmaf(a1, inv, bv0.y);
  float v2 = fmaf(a2, inv, bv0.z), v3 = fmaf(a3, inv, bv0.w);
  float v4 = fmaf(a4, inv, bv1.x), v5 = fmaf(a5, inv, bv1.y);
  float v6 = fmaf(a6, inv, bv1.z), v7 = fmaf(a7, inv, bv1.w);
  bool act = (k < 5);
  float m = act ? fmaxf(fmaxf(fmaxf(v0, v1), fmaxf(v2, v3)),
                        fmaxf(fmaxf(v4, v5), fmaxf(v6, v7))) : -INFINITY;
#pragma unroll
  for (int off = 1; off < 8; off <<= 1) m = fmaxf(m, __shfl_xor(m, off, 64));
  float ex = act ? (__expf(v0 - m) + __expf(v1 - m) + __expf(v2 - m) + __expf(v3 - m) +
                    __expf(v4 - m) + __expf(v5 - m) + __expf(v6 - m) + __expf(v7 - m)) : 0.f;
#pragma unroll
  for (int off = 1; off < 8; off <<= 1) ex += __shfl_xor(ex, off, 64);
  if (act) {
    float lls = m + logf(ex);
    float4 s0; s0.x = v0 - lls; s0.y = v1 - lls; s0.z = v2 - lls; s0.w = v3 - lls;
    float4 s1; s1.x = v4 - lls; s1.y = v5 - lls; s1.z = v6 - lls; s1.w = v7 - lls;
    float* op = out + (size_t)node * C2 + (k << 3);
    ((float4*)op)[0] = s0; ((float4*)op)[1] = s1;
  }
}

// ---------- launch ----------
extern "C" void kernel_launch(void* const* d_in, const int* in_sizes, int n_in,
                              void* d_out, int out_size, void* d_ws, size_t ws_size,
                              hipStream_t stream) {
  const float* x    = (const float*)d_in[0];
  const float* W1   = (const float*)d_in[1];
  const float* as1w = (const float*)d_in[2];
  const float* ad1w = (const float*)d_in[3];
  const float* b1   = (const float*)d_in[4];
  const float* W2   = (const float*)d_in[5];
  const float* as2w = (const float*)d_in[6];
  const float* ad2w = (const float*)d_in[7];
  const float* b2   = (const float*)d_in[8];
  const int*   ei   = (const int*)d_in[9];

  float* out   = (float*)d_out;
  float* outls = out;                    // [N,40] log_softmax
  float* emb   = out + (long)NN * C2;    // [N,64] emb

  char* wsb = (char*)d_ws;
  __half* h1   = (__half*)wsb; wsb += sizeof(__half) * (size_t)NN * D1;
  __half* h2   = (__half*)wsb; wsb += sizeof(__half) * ((size_t)NN * 64 + 64);
  __half* ash1 = (__half*)wsb; wsb += sizeof(__half) * (size_t)NN * H1;
  float* adst1 = (float*)wsb; wsb += sizeof(float) * (size_t)NN * H1;
  float* adst2 = (float*)wsb; wsb += sizeof(float) * (size_t)NN;
  int2* rowrng = (int2*)wsb;  wsb += sizeof(int2) * (size_t)NN;
  int* perm    = (int*)wsb;   wsb += sizeof(int) * (size_t)NN;
  int* gcur    = (int*)wsb;   wsb += sizeof(int) * (NBKT + 4);
  int* dhist   = (int*)wsb;   wsb += sizeof(int) * DB * DSTR;
  int* dcur    = (int*)wsb;   wsb += sizeof(int) * DB * DSTR;
  __half* Wf1  = (__half*)wsb; wsb += sizeof(__half) * 4 * 5 * 64 * 8;
  __half* Wf2  = (__half*)wsb; wsb += sizeof(__half) * 2 * 3 * 64 * 8;
  int* ecsr    = (int*)wsb;   wsb += sizeof(int) * (size_t)NBKT * BCAPP;

  hipMemsetAsync(gcur, 0, sizeof(int) * (NBKT + 4 + 2 * DB * DSTR), stream);
  // k1: scatter || prep
  k1_kernel<<<NBB + PREPB, 256, 0, stream>>>(ei, gcur, ecsr,
                                             W1, as1w, ad1w, W2, as2w, ad2w, Wf1, Wf2);
  // k2: bucket2csr (padded) || gemm1
  k2_kernel<<<NBKT + G1B, 256, 0, stream>>>(gcur, rowrng, ecsr, dhist,
                                            x, Wf1, h1, ash1, adst1);
  // k3: degree-balanced perm
  k3_kernel<<<(NN + 255) / 256, 256, 0, stream>>>(rowrng, dhist, dcur, perm);
  // layer-1 aggregation
  agg1_kernel<<<NN / 32, 256, 0, stream>>>(perm, rowrng, ecsr, ash1, adst1, h1, b1, emb);
  // layer 2
  gemm2_kernel<<<(NN + 63) / 64, 256, 0, stream>>>(emb, Wf2, h2, adst2);
  agg2_kernel<<<NN / 32, 256, 0, stream>>>(perm, rowrng, ecsr, adst2, h2, b2, outls);
}